// Round 2
// baseline (54076.447 us; speedup 1.0000x reference)
//
#include <hip/hip_runtime.h>
#include <cstdint>
#include <cstddef>

#define T_N    32768
#define INP_N  1024
#define HID_N  1024
#define OUT_N  7

// ===========================================================================
// GEMM: C[m][n] = act( sum_k A[m][k]*B[n][k] + bias[n] )
//   A: M x K row-major (lda), B: N x K row-major (ldb), C: M x N (stride N)
//   128x128 tile, 256 threads, 8x8 micro-tile, K-step 16.
// ===========================================================================
template<bool TANH>
__global__ __launch_bounds__(256)
void gemm_bt(const float* __restrict__ A, int lda,
             const float* __restrict__ B, int ldb,
             const float* __restrict__ bias,
             float* __restrict__ C, int N, int K)
{
  __shared__ __align__(16) float As[16][128];
  __shared__ __align__(16) float Bs[16][128];

  const int tid = threadIdx.x;
  const int bm0 = blockIdx.y * 128;
  const int bn0 = blockIdx.x * 128;
  const int tx  = tid & 15;        // micro-tile col group
  const int ty  = tid >> 4;        // micro-tile row group
  const int lm  = tid >> 1;        // staging row 0..127
  const int kq  = (tid & 1) * 8;   // staging k offset 0 or 8

  float acc[8][8];
#pragma unroll
  for (int i = 0; i < 8; ++i)
#pragma unroll
    for (int j = 0; j < 8; ++j) acc[i][j] = 0.f;

  const float* Arow = A + (size_t)(bm0 + lm) * lda + kq;
  const float* Brow = B + (size_t)(bn0 + lm) * ldb + kq;

  for (int k0 = 0; k0 < K; k0 += 16) {
    // issue global loads before the barrier so latency overlaps prior compute
    float4 va = *(const float4*)(Arow + k0);
    float4 vb = *(const float4*)(Arow + k0 + 4);
    float4 wa = *(const float4*)(Brow + k0);
    float4 wb = *(const float4*)(Brow + k0 + 4);
    __syncthreads();   // previous iteration's LDS reads complete
    As[kq+0][lm]=va.x; As[kq+1][lm]=va.y; As[kq+2][lm]=va.z; As[kq+3][lm]=va.w;
    As[kq+4][lm]=vb.x; As[kq+5][lm]=vb.y; As[kq+6][lm]=vb.z; As[kq+7][lm]=vb.w;
    Bs[kq+0][lm]=wa.x; Bs[kq+1][lm]=wa.y; Bs[kq+2][lm]=wa.z; Bs[kq+3][lm]=wa.w;
    Bs[kq+4][lm]=wb.x; Bs[kq+5][lm]=wb.y; Bs[kq+6][lm]=wb.z; Bs[kq+7][lm]=wb.w;
    __syncthreads();
#pragma unroll
    for (int kk = 0; kk < 16; ++kk) {
      float4 a0 = *(const float4*)&As[kk][ty*8];
      float4 a1 = *(const float4*)&As[kk][ty*8+4];
      float4 b0 = *(const float4*)&Bs[kk][tx*8];
      float4 b1 = *(const float4*)&Bs[kk][tx*8+4];
      float av[8] = {a0.x,a0.y,a0.z,a0.w,a1.x,a1.y,a1.z,a1.w};
      float bv[8] = {b0.x,b0.y,b0.z,b0.w,b1.x,b1.y,b1.z,b1.w};
#pragma unroll
      for (int i = 0; i < 8; ++i)
#pragma unroll
        for (int j = 0; j < 8; ++j)
          acc[i][j] = fmaf(av[i], bv[j], acc[i][j]);
    }
  }

  float bv[8];
#pragma unroll
  for (int j = 0; j < 8; ++j) bv[j] = bias[bn0 + tx*8 + j];

#pragma unroll
  for (int i = 0; i < 8; ++i) {
    float vo[8];
#pragma unroll
    for (int j = 0; j < 8; ++j) {
      float v = acc[i][j] + bv[j];
      vo[j] = TANH ? tanhf(v) : v;
    }
    float4 o0 = make_float4(vo[0],vo[1],vo[2],vo[3]);
    float4 o1 = make_float4(vo[4],vo[5],vo[6],vo[7]);
    float* cp = &C[(size_t)(bm0 + ty*8 + i) * N + bn0 + tx*8];
    *(float4*)cp = o0;
    *(float4*)(cp + 4) = o1;
  }
}

// ===========================================================================
// Sequential scan: h_t = tanh(Wh_prev @ h_{t-1} + cc_t), t = 0..T-1, h_{-1}=0
//   32 persistent WGs x 512 threads (8 waves). WG g owns output rows
//   [32g, 32g+32). Wave wv covers h-columns [128wv, 128wv+128); lane
//   (r = ln&31, h2 = ln>>5) holds W[32g+r][128wv+64*h2 .. +63] in 64 VGPRs.
//   Cross-WG exchange: hist pre-memset to 0xFFFFFFFF (NaN sentinel); the
//   rotating finalizer wave publishes rows via agent-scope relaxed atomic
//   stores; consumers NaN-poll exactly their 128-col slice with agent-scope
//   atomic loads. The polled registers ARE the data -> no flags, no fences.
// ===========================================================================
#define SCAN_G     32
#define SCAN_WGSZ  512
#define SCAN_WAVES 8
#define ROWS_WG    32   // HID_N / SCAN_G

__global__ __launch_bounds__(SCAN_WGSZ)
void scan_kernel(const float* __restrict__ Wh,   // (1024, 2048), cols [0,1024)
                 const float* __restrict__ cc,   // (T, 1024)
                 float* __restrict__ hist)       // (T, 1024), pre-filled 0xFF
{
  const int g   = blockIdx.x;
  const int tid = threadIdx.x;
  const int wv  = tid >> 6;
  const int ln  = tid & 63;
  const int r   = ln & 31;
  const int h2  = ln >> 5;
  const int row = g * ROWS_WG + r;
  const int colbase = wv * 128 + h2 * 64;

  __shared__ __align__(16) float hseg[SCAN_WAVES * 128];
  __shared__ float part[2][16][ROWS_WG];

  // W slice into registers: 16 x float4 = 64 values
  float4 wreg[16];
  {
    const float* wp = Wh + (size_t)row * (2 * HID_N) + colbase;
#pragma unroll
    for (int q = 0; q < 16; ++q) wreg[q] = *(const float4*)(wp + 4*q);
  }

  // cc prefetch: wave wv first finalizes step t = wv
  float ccp = 0.f;
  if (ln < ROWS_WG) ccp = cc[(size_t)wv * HID_N + g * ROWS_WG + ln];

  uint32_t* histu = (uint32_t*)hist;

  for (int t = 0; t < T_N; ++t) {
    float a, b;
    if (t > 0) {
      const uint32_t* src = histu + (size_t)(t - 1) * HID_N + wv * 128;
      uint32_t au, bu;
      for (;;) {
        au = __hip_atomic_load(src + ln,      __ATOMIC_RELAXED, __HIP_MEMORY_SCOPE_AGENT);
        bu = __hip_atomic_load(src + 64 + ln, __ATOMIC_RELAXED, __HIP_MEMORY_SCOPE_AGENT);
        if (__all((au != 0xFFFFFFFFu) && (bu != 0xFFFFFFFFu))) break;
      }
      a = __uint_as_float(au);
      b = __uint_as_float(bu);
    } else {
      a = 0.f; b = 0.f;
    }

    // stage slice for intra-wave broadcast (wave-private LDS segment)
    hseg[wv*128 + ln]      = a;
    hseg[wv*128 + 64 + ln] = b;

    // 64-col partial dot for this lane's row
    float p0 = 0.f, p1 = 0.f, p2 = 0.f, p3 = 0.f;
#pragma unroll
    for (int q = 0; q < 16; ++q) {
      float4 h4 = *(const float4*)&hseg[colbase + q*4];
      p0 = fmaf(wreg[q].x, h4.x, p0);
      p1 = fmaf(wreg[q].y, h4.y, p1);
      p2 = fmaf(wreg[q].z, h4.z, p2);
      p3 = fmaf(wreg[q].w, h4.w, p3);
    }
    part[t & 1][wv*2 + h2][r] = (p0 + p1) + (p2 + p3);
    __syncthreads();

    // rotating finalizer wave: reduce 16 partials, tanh, publish
    if (wv == (t & 7)) {
      if (ln < ROWS_WG) {
        float s = 0.f;
#pragma unroll
        for (int idx = 0; idx < 16; ++idx) s += part[t & 1][idx][ln];
        float val = tanhf(s + ccp);
        __hip_atomic_store(histu + (size_t)t * HID_N + g * ROWS_WG + ln,
                           __float_as_uint(val),
                           __ATOMIC_RELAXED, __HIP_MEMORY_SCOPE_AGENT);
        int tn = t + SCAN_WAVES;
        ccp = (tn < T_N) ? cc[(size_t)tn * HID_N + g * ROWS_WG + ln] : 0.f;
      }
    }
  }
}

// ===========================================================================
// Output pass: out = mean_t softmax(hist[t] @ Wo.T + bo)
//   One wave per row (grid-stride). Wo/bias stay L1/L2 resident.
// ===========================================================================
__global__ __launch_bounds__(256)
void out_kernel(const float* __restrict__ hist,
                const float* __restrict__ Wo,   // (7, 1024)
                const float* __restrict__ bo,
                float* __restrict__ out)
{
  const int wv = threadIdx.x >> 6;
  const int ln = threadIdx.x & 63;
  const int gw = blockIdx.x * 4 + wv;
  const int nw = gridDim.x * 4;

  float bor[OUT_N];
#pragma unroll
  for (int o = 0; o < OUT_N; ++o) bor[o] = bo[o];

  float acc[OUT_N];
#pragma unroll
  for (int o = 0; o < OUT_N; ++o) acc[o] = 0.f;

  for (int t = gw; t < T_N; t += nw) {
    const float* hrow = hist + (size_t)t * HID_N + ln * 16;
    float4 h0 = *(const float4*)(hrow);
    float4 h1 = *(const float4*)(hrow + 4);
    float4 h2 = *(const float4*)(hrow + 8);
    float4 h3 = *(const float4*)(hrow + 12);

    float z[OUT_N];
#pragma unroll
    for (int o = 0; o < OUT_N; ++o) {
      const float* wrow = Wo + (size_t)o * HID_N + ln * 16;
      float4 w0 = *(const float4*)(wrow);
      float4 w1 = *(const float4*)(wrow + 4);
      float4 w2 = *(const float4*)(wrow + 8);
      float4 w3 = *(const float4*)(wrow + 12);
      float s;
      s  = h0.x*w0.x + h0.y*w0.y + h0.z*w0.z + h0.w*w0.w;
      s += h1.x*w1.x + h1.y*w1.y + h1.z*w1.z + h1.w*w1.w;
      s += h2.x*w2.x + h2.y*w2.y + h2.z*w2.z + h2.w*w2.w;
      s += h3.x*w3.x + h3.y*w3.y + h3.z*w3.z + h3.w*w3.w;
      z[o] = s;
    }
#pragma unroll
    for (int o = 0; o < OUT_N; ++o) {
#pragma unroll
      for (int off = 1; off < 64; off <<= 1)
        z[o] += __shfl_xor(z[o], off);
      z[o] += bor[o];
    }
    float m = z[0];
#pragma unroll
    for (int o = 1; o < OUT_N; ++o) m = fmaxf(m, z[o]);
    float e[OUT_N], s = 0.f;
#pragma unroll
    for (int o = 0; o < OUT_N; ++o) { e[o] = expf(z[o] - m); s += e[o]; }
    float inv = 1.f / s;
#pragma unroll
    for (int o = 0; o < OUT_N; ++o) acc[o] = fmaf(e[o], inv, acc[o]);
  }

  if (ln == 0) {
#pragma unroll
    for (int o = 0; o < OUT_N; ++o)
      atomicAdd(&out[o], acc[o] * (1.0f / (float)T_N));
  }
}

// ===========================================================================
extern "C" void kernel_launch(void* const* d_in, const int* in_sizes, int n_in,
                              void* d_out, int out_size, void* d_ws, size_t ws_size,
                              hipStream_t stream)
{
  const float* U  = (const float*)d_in[0];   // (T, INP)
  const float* Wi = (const float*)d_in[1];   // (HID, INP)
  const float* bi = (const float*)d_in[2];   // (HID)
  const float* Wh = (const float*)d_in[3];   // (HID, 2*HID)
  const float* bh = (const float*)d_in[4];   // (HID)
  const float* Wo = (const float*)d_in[5];   // (OUT, HID)
  const float* bo = (const float*)d_in[6];   // (OUT)
  float* out = (float*)d_out;

  const size_t mat = (size_t)T_N * HID_N;    // 33.5M floats = 134 MB
  float* hc = (float*)d_ws;                  // GEMM1 out; later reused as hist
  float* cc = hc + mat;                      // GEMM2 out
  float* hist = hc;                          // alias: hc dead after GEMM2

  dim3 gg(HID_N / 128, T_N / 128);

  // 1) hc = tanh(U @ Wi^T + bi)
  gemm_bt<true ><<<gg, 256, 0, stream>>>(U,  INP_N, Wi, INP_N, bi, hc, HID_N, INP_N);
  // 2) cc = hc @ Wh_cur^T + bh   (Wh_cur = Wh[:, HID:], ldb = 2*HID)
  gemm_bt<false><<<gg, 256, 0, stream>>>(hc, HID_N, Wh + HID_N, 2 * HID_N, bh, cc, HID_N, HID_N);
  // 3) fill hist with the NaN sentinel (0xFFFFFFFF), then run the scan
  hipMemsetAsync(hist, 0xFF, mat * sizeof(float), stream);
  scan_kernel<<<SCAN_G, SCAN_WGSZ, 0, stream>>>(Wh, cc, hist);
  // 4) out = mean_t softmax(hist[t] @ Wo^T + bo)
  hipMemsetAsync(out, 0, OUT_N * sizeof(float), stream);
  out_kernel<<<1024, 256, 0, stream>>>(hist, Wo, bo, out);
}

// Round 6
// 46998.746 us; speedup vs baseline: 1.1506x; 1.1506x over previous
//
#include <hip/hip_runtime.h>
#include <cstdint>
#include <cstddef>

#define T_N    32768
#define INP_N  1024
#define HID_N  1024
#define OUT_N  7
#define SENT   0xFFFFFFFFu
#define RING   16

// ===========================================================================
// GEMM: C[m][n] = act( sum_k A[m][k]*B[n][k] + bias[n] )  (r2-proven)
// ===========================================================================
template<bool TANH>
__global__ __launch_bounds__(256)
void gemm_bt(const float* __restrict__ A, int lda,
             const float* __restrict__ B, int ldb,
             const float* __restrict__ bias,
             float* __restrict__ C, int N, int K)
{
  __shared__ __align__(16) float As[16][128];
  __shared__ __align__(16) float Bs[16][128];

  const int tid = threadIdx.x;
  const int bm0 = blockIdx.y * 128;
  const int bn0 = blockIdx.x * 128;
  const int tx  = tid & 15;
  const int ty  = tid >> 4;
  const int lm  = tid >> 1;
  const int kq  = (tid & 1) * 8;

  float acc[8][8];
#pragma unroll
  for (int i = 0; i < 8; ++i)
#pragma unroll
    for (int j = 0; j < 8; ++j) acc[i][j] = 0.f;

  const float* Arow = A + (size_t)(bm0 + lm) * lda + kq;
  const float* Brow = B + (size_t)(bn0 + lm) * ldb + kq;

  for (int k0 = 0; k0 < K; k0 += 16) {
    float4 va = *(const float4*)(Arow + k0);
    float4 vb = *(const float4*)(Arow + k0 + 4);
    float4 wa = *(const float4*)(Brow + k0);
    float4 wb = *(const float4*)(Brow + k0 + 4);
    __syncthreads();
    As[kq+0][lm]=va.x; As[kq+1][lm]=va.y; As[kq+2][lm]=va.z; As[kq+3][lm]=va.w;
    As[kq+4][lm]=vb.x; As[kq+5][lm]=vb.y; As[kq+6][lm]=vb.z; As[kq+7][lm]=vb.w;
    Bs[kq+0][lm]=wa.x; Bs[kq+1][lm]=wa.y; Bs[kq+2][lm]=wa.z; Bs[kq+3][lm]=wa.w;
    Bs[kq+4][lm]=wb.x; Bs[kq+5][lm]=wb.y; Bs[kq+6][lm]=wb.z; Bs[kq+7][lm]=wb.w;
    __syncthreads();
#pragma unroll
    for (int kk = 0; kk < 16; ++kk) {
      float4 a0 = *(const float4*)&As[kk][ty*8];
      float4 a1 = *(const float4*)&As[kk][ty*8+4];
      float4 b0 = *(const float4*)&Bs[kk][tx*8];
      float4 b1 = *(const float4*)&Bs[kk][tx*8+4];
      float av[8] = {a0.x,a0.y,a0.z,a0.w,a1.x,a1.y,a1.z,a1.w};
      float bv[8] = {b0.x,b0.y,b0.z,b0.w,b1.x,b1.y,b1.z,b1.w};
#pragma unroll
      for (int i = 0; i < 8; ++i)
#pragma unroll
        for (int j = 0; j < 8; ++j)
          acc[i][j] = fmaf(av[i], bv[j], acc[i][j]);
    }
  }

  float bv[8];
#pragma unroll
  for (int j = 0; j < 8; ++j) bv[j] = bias[bn0 + tx*8 + j];

#pragma unroll
  for (int i = 0; i < 8; ++i) {
    float vo[8];
#pragma unroll
    for (int j = 0; j < 8; ++j) {
      float v = acc[i][j] + bv[j];
      vo[j] = TANH ? tanhf(v) : v;
    }
    float4 o0 = make_float4(vo[0],vo[1],vo[2],vo[3]);
    float4 o1 = make_float4(vo[4],vo[5],vo[6],vo[7]);
    float* cp = &C[(size_t)(bm0 + ty*8 + i) * N + bn0 + tx*8];
    *(float4*)cp = o0;
    *(float4*)(cp + 4) = o1;
  }
}

// ===========================================================================
// Sequential scan v3: h_t = tanh(Wh_prev @ h_{t-1} + cc_t).
//   32 WGs x 512 threads; WG g owns rows [32g, 32g+32).  Lane (r=ln&31,
//   h2=ln>>5) of wave wv holds W[32g+r][128wv+64h2 .. +63] in 64 VGPRs.
//
//   TAGGED mode: communication via ring mailbox mb64[RING][1024] of 64-bit
//   (tag,value) pairs (128 KB -> permanently LLC-hot; r2 polled the 134 MB
//   hist buffer whose lines thrashed the 256 MB LLC -> HBM-latency polls).
//   Publisher of step t atomically stores ((t<<32)|bits(h)); consumers poll
//   until tag==t-1.  Stale entries are self-identifying -> no slot resets,
//   no sentinel-ordering proofs.  Mailbox memset to 0xFF per launch kills
//   cross-replay staleness.  hist becomes write-only (nontemporal).
//   Fallback (!TAGGED, ws too small): exact r2-proven sentinel protocol.
// ===========================================================================
#define SCAN_G     32
#define SCAN_WGSZ  512
#define ROWS_WG    32   // HID_N / SCAN_G

template<bool TAGGED>
__global__ __launch_bounds__(SCAN_WGSZ, 2)   // VGPR cap 256: keep W resident (r2: VGPR=56 => W re-fetched every step)
void scan_kernel(const float* __restrict__ Wh,   // (1024, 2048), cols [0,1024)
                 const float* __restrict__ cc,   // (T, 1024)
                 float* __restrict__ hist,       // (T, 1024) write-only
                 void* __restrict__ mb_)         // ring mailbox / hist alias
{
  const int g   = blockIdx.x;
  const int tid = threadIdx.x;
  const int wv  = tid >> 6;
  const int ln  = tid & 63;
  const int r   = ln & 31;
  const int h2  = ln >> 5;
  const int row = g * ROWS_WG + r;
  const int colbase = wv * 128 + h2 * 64;

  __shared__ __align__(16) float hseg[8 * 128];
  __shared__ float part[2][16][ROWS_WG];

  uint64_t* mb64 = (uint64_t*)mb_;   // TAGGED
  uint32_t* mb32 = (uint32_t*)mb_;   // fallback (aliases hist)

  // W slice into registers: 16 x float4 = 64 values, live across the loop
  float4 wreg[16];
  {
    const float* wp = Wh + (size_t)row * (2 * HID_N) + colbase;
#pragma unroll
    for (int q = 0; q < 16; ++q) wreg[q] = *(const float4*)(wp + 4*q);
  }

  // cc prefetch: wave wv first finalizes step t = wv
  float ccp = 0.f;
  if (ln < ROWS_WG) ccp = cc[(size_t)wv * HID_N + g * ROWS_WG + ln];

  for (int t = 0; t < T_N; ++t) {
    if (t > 0) {
      if (TAGGED) {
        // lane ln owns cols (2ln, 2ln+1) of its wave's 128-col slice
        const uint64_t* src =
            mb64 + (size_t)((t - 1) & (RING - 1)) * HID_N + wv * 128;
        const uint32_t want = (uint32_t)(t - 1);
        uint64_t v0, v1;
        for (;;) {
          v0 = __hip_atomic_load(src + 2*ln,     __ATOMIC_RELAXED, __HIP_MEMORY_SCOPE_AGENT);
          v1 = __hip_atomic_load(src + 2*ln + 1, __ATOMIC_RELAXED, __HIP_MEMORY_SCOPE_AGENT);
          if (__all(((uint32_t)(v0 >> 32) == want) & ((uint32_t)(v1 >> 32) == want))) break;
        }
        hseg[wv*128 + 2*ln]     = __uint_as_float((uint32_t)v0);
        hseg[wv*128 + 2*ln + 1] = __uint_as_float((uint32_t)v1);
      } else {
        const uint64_t* src =
            (const uint64_t*)(mb32 + (size_t)(t - 1) * HID_N + wv * 128);
        uint64_t v;
        for (;;) {
          v = __hip_atomic_load(src + ln, __ATOMIC_RELAXED, __HIP_MEMORY_SCOPE_AGENT);
          if (__all(((uint32_t)v != SENT) && ((uint32_t)(v >> 32) != SENT))) break;
        }
        hseg[wv*128 + 2*ln]     = __uint_as_float((uint32_t)v);
        hseg[wv*128 + 2*ln + 1] = __uint_as_float((uint32_t)(v >> 32));
      }
    } else {
      hseg[wv*128 + 2*ln]     = 0.f;
      hseg[wv*128 + 2*ln + 1] = 0.f;
    }

    // 64-col partial dot for this lane's row (hseg reads are broadcasts)
    float p0 = 0.f, p1 = 0.f, p2 = 0.f, p3 = 0.f;
#pragma unroll
    for (int q = 0; q < 16; ++q) {
      float4 h4 = *(const float4*)&hseg[colbase + q*4];
      p0 = fmaf(wreg[q].x, h4.x, p0);
      p1 = fmaf(wreg[q].y, h4.y, p1);
      p2 = fmaf(wreg[q].z, h4.z, p2);
      p3 = fmaf(wreg[q].w, h4.w, p3);
    }
    part[t & 1][wv*2 + h2][r] = (p0 + p1) + (p2 + p3);
    __syncthreads();

    // rotating finalizer wave: tree-reduce 16 partials, fast tanh, publish
    if (wv == (t & 7) && ln < ROWS_WG) {
      float s[16];
#pragma unroll
      for (int i = 0; i < 16; ++i) s[i] = part[t & 1][i][ln];
#pragma unroll
      for (int d = 8; d > 0; d >>= 1)
#pragma unroll
        for (int i = 0; i < d; ++i) s[i] += s[i + d];
      float x = s[0] + ccp;
      // tanh(x) = 1 - 2/(exp(2x)+1); ~1e-6 abs err, exact at 0/+-inf.
      // Recurrence is contractive (||Wh_prev||_2 ~ 0.82) -> no amplification.
      float ex  = __expf(2.0f * x);
      float val = 1.0f - 2.0f * __builtin_amdgcn_rcpf(ex + 1.0f);

      if (TAGGED) {
        uint64_t pkt = ((uint64_t)(uint32_t)t << 32) | (uint64_t)__float_as_uint(val);
        __hip_atomic_store(mb64 + (size_t)(t & (RING - 1)) * HID_N + g * ROWS_WG + ln,
                           pkt, __ATOMIC_RELAXED, __HIP_MEMORY_SCOPE_AGENT);
        // history for the output pass: pure streaming store
        __builtin_nontemporal_store(val, hist + (size_t)t * HID_N + g * ROWS_WG + ln);
      } else {
        // fallback: publish IS the history write (mb32 aliases hist)
        __hip_atomic_store(mb32 + (size_t)t * HID_N + g * ROWS_WG + ln,
                           __float_as_uint(val),
                           __ATOMIC_RELAXED, __HIP_MEMORY_SCOPE_AGENT);
      }
      int tn = t + 8;
      if (tn < T_N)
        ccp = __builtin_nontemporal_load(cc + (size_t)tn * HID_N + g * ROWS_WG + ln);
    }
  }
}

// ===========================================================================
// Output pass: out = mean_t softmax(hist[t] @ Wo.T + bo)   (r2-proven)
// ===========================================================================
__global__ __launch_bounds__(256)
void out_kernel(const float* __restrict__ hist,
                const float* __restrict__ Wo,
                const float* __restrict__ bo,
                float* __restrict__ out)
{
  const int wv = threadIdx.x >> 6;
  const int ln = threadIdx.x & 63;
  const int gw = blockIdx.x * 4 + wv;
  const int nw = gridDim.x * 4;

  float bor[OUT_N];
#pragma unroll
  for (int o = 0; o < OUT_N; ++o) bor[o] = bo[o];

  float acc[OUT_N];
#pragma unroll
  for (int o = 0; o < OUT_N; ++o) acc[o] = 0.f;

  for (int t = gw; t < T_N; t += nw) {
    const float* hrow = hist + (size_t)t * HID_N + ln * 16;
    float4 h0 = *(const float4*)(hrow);
    float4 h1 = *(const float4*)(hrow + 4);
    float4 h2 = *(const float4*)(hrow + 8);
    float4 h3 = *(const float4*)(hrow + 12);

    float z[OUT_N];
#pragma unroll
    for (int o = 0; o < OUT_N; ++o) {
      const float* wrow = Wo + (size_t)o * HID_N + ln * 16;
      float4 w0 = *(const float4*)(wrow);
      float4 w1 = *(const float4*)(wrow + 4);
      float4 w2 = *(const float4*)(wrow + 8);
      float4 w3 = *(const float4*)(wrow + 12);
      float s;
      s  = h0.x*w0.x + h0.y*w0.y + h0.z*w0.z + h0.w*w0.w;
      s += h1.x*w1.x + h1.y*w1.y + h1.z*w1.z + h1.w*w1.w;
      s += h2.x*w2.x + h2.y*w2.y + h2.z*w2.z + h2.w*w2.w;
      s += h3.x*w3.x + h3.y*w3.y + h3.z*w3.z + h3.w*w3.w;
      z[o] = s;
    }
#pragma unroll
    for (int o = 0; o < OUT_N; ++o) {
#pragma unroll
      for (int off = 1; off < 64; off <<= 1)
        z[o] += __shfl_xor(z[o], off);
      z[o] += bor[o];
    }
    float m = z[0];
#pragma unroll
    for (int o = 1; o < OUT_N; ++o) m = fmaxf(m, z[o]);
    float e[OUT_N], s = 0.f;
#pragma unroll
    for (int o = 0; o < OUT_N; ++o) { e[o] = expf(z[o] - m); s += e[o]; }
    float inv = 1.f / s;
#pragma unroll
    for (int o = 0; o < OUT_N; ++o) acc[o] = fmaf(e[o], inv, acc[o]);
  }

  if (ln == 0) {
#pragma unroll
    for (int o = 0; o < OUT_N; ++o)
      atomicAdd(&out[o], acc[o] * (1.0f / (float)T_N));
  }
}

// ===========================================================================
extern "C" void kernel_launch(void* const* d_in, const int* in_sizes, int n_in,
                              void* d_out, int out_size, void* d_ws, size_t ws_size,
                              hipStream_t stream)
{
  const float* U  = (const float*)d_in[0];   // (T, INP)
  const float* Wi = (const float*)d_in[1];   // (HID, INP)
  const float* bi = (const float*)d_in[2];   // (HID)
  const float* Wh = (const float*)d_in[3];   // (HID, 2*HID)
  const float* bh = (const float*)d_in[4];   // (HID)
  const float* Wo = (const float*)d_in[5];   // (OUT, HID)
  const float* bo = (const float*)d_in[6];   // (OUT)
  float* out = (float*)d_out;

  const size_t mat = (size_t)T_N * HID_N;    // 33.5M floats = 134 MB
  float* hc   = (float*)d_ws;                // GEMM1 out; later reused as hist
  float* cc   = hc + mat;                    // GEMM2 out
  float* hist = hc;                          // alias: hc dead after GEMM2

  const size_t mb_bytes = (size_t)RING * HID_N * sizeof(uint64_t);  // 128 KB
  const size_t need     = 2 * mat * sizeof(float) + mb_bytes;
  const bool tagged     = (ws_size >= need);
  void* mb = tagged ? (void*)(cc + mat) : (void*)hist;

  dim3 gg(HID_N / 128, T_N / 128);

  // 1) hc = tanh(U @ Wi^T + bi)
  gemm_bt<true ><<<gg, 256, 0, stream>>>(U,  INP_N, Wi, INP_N, bi, hc, HID_N, INP_N);
  // 2) cc = hc @ Wh_cur^T + bh   (Wh_cur = Wh[:, HID:], ldb = 2*HID)
  gemm_bt<false><<<gg, 256, 0, stream>>>(hc, HID_N, Wh + HID_N, 2 * HID_N, bh, cc, HID_N, HID_N);
  // 3) wipe the mailbox (tags/sentinels), then run the scan
  if (tagged) {
    hipMemsetAsync(mb, 0xFF, mb_bytes, stream);
    scan_kernel<true ><<<SCAN_G, SCAN_WGSZ, 0, stream>>>(Wh, cc, hist, mb);
  } else {
    hipMemsetAsync(mb, 0xFF, mat * sizeof(float), stream);
    scan_kernel<false><<<SCAN_G, SCAN_WGSZ, 0, stream>>>(Wh, cc, hist, mb);
  }
  // 4) out = mean_t softmax(hist[t] @ Wo^T + bo)
  hipMemsetAsync(out, 0, OUT_N * sizeof(float), stream);
  out_kernel<<<1024, 256, 0, stream>>>(hist, Wo, bo, out);
}